// Round 1
// baseline (1527.463 us; speedup 1.0000x reference)
//
#include <hip/hip_runtime.h>
#include <stdint.h>

typedef unsigned int u32;
typedef unsigned short u16;

#define GRIDW 300
#define XS 156   // padded X row stride (floats)

// ---- workspace layout (bytes) ----
#define WOFF_WEFF 0u
#define WOFF_VD   16384u
#define WOFF_W1P  32768u            // 128*152*4 = 77824 bytes
#define WOFF_TC   131072u           // 3*300*300*48*2 = 25920000 bytes
#define WOFF_TD   26083328u         // 3*300*300*16*2 = 8640000 bytes
#define WS_FULL   34723328u

__device__ __forceinline__ float bflo(u32 w){ return __uint_as_float(w<<16); }
__device__ __forceinline__ float bfhi(u32 w){ return __uint_as_float(w & 0xffff0000u); }
__device__ __forceinline__ u16 f2bf(float f){
  u32 u = __float_as_uint(f);
  u32 r = (u + 0x7fffu + ((u>>16)&1u)) >> 16;
  return (u16)r;
}

// ---- prep: Weff = feat_w * vconst ; vd ; W1 padded to 152 cols ----
__global__ void prep_k(const float* __restrict__ feat_w,
                       const float* __restrict__ vmc_vec,
                       const float* __restrict__ vmd_vec,
                       const float* __restrict__ w1,
                       float* __restrict__ Weff, float* __restrict__ vd,
                       float* __restrict__ W1p)
{
  const int total = 3888 + 48 + 128*152;
  for (int t = blockIdx.x*blockDim.x + threadIdx.x; t < total; t += gridDim.x*blockDim.x) {
    if (t < 3888) {
      int k = t % 144;
      float v = 0.5f*(vmc_vec[k*300 + 149] + vmc_vec[k*300 + 150]);
      Weff[t] = feat_w[t] * v;
    } else if (t < 3936) {
      int k = t - 3888;
      vd[k] = 0.5f*(vmd_vec[k*300 + 149] + vmd_vec[k*300 + 150]);
    } else {
      int j = t - 3936;
      int h = j / 152, c = j - h*152;
      W1p[j] = (c < 150) ? w1[h*150 + c] : 0.f;
    }
  }
}

// ---- transpose (3,C,300,300) f32 -> (3,300,300,C) bf16 ----
__global__ void transpose_k(const float* __restrict__ src, u16* __restrict__ dst, int C)
{
  __shared__ float tile[48*301];
  int i = blockIdx.x / 300, y = blockIdx.x % 300;
  const float* sp = src + (size_t)i*C*90000 + (size_t)y*300;
  for (int t = threadIdx.x; t < C*300; t += 256) {
    int r = t / 300, xx = t - r*300;
    tile[r*301 + xx] = sp[(size_t)r*90000 + xx];
  }
  __syncthreads();
  u16* dp = dst + (size_t)(i*300 + y)*300*C;
  for (int t = threadIdx.x; t < 300*C; t += 256) {
    int xx = t / C, r = t - xx*C;
    dp[t] = f2bf(tile[r*301 + xx]);
  }
}

__device__ __forceinline__ void lerp8(const u16* r00, const u16* r01,
                                      const u16* r10, const u16* r11,
                                      int off, float wx, float wy, float m[8])
{
  uint4 A = *reinterpret_cast<const uint4*>(r00+off);
  uint4 Bv = *reinterpret_cast<const uint4*>(r01+off);
  uint4 Cv = *reinterpret_cast<const uint4*>(r10+off);
  uint4 Dv = *reinterpret_cast<const uint4*>(r11+off);
  u32 aw[4]={A.x,A.y,A.z,A.w};
  u32 bw[4]={Bv.x,Bv.y,Bv.z,Bv.w};
  u32 cw[4]={Cv.x,Cv.y,Cv.z,Cv.w};
  u32 dw[4]={Dv.x,Dv.y,Dv.z,Dv.w};
#pragma unroll
  for (int w=0; w<4; ++w){
    float a0=bflo(aw[w]), a1=bfhi(aw[w]);
    float b0=bflo(bw[w]), b1=bfhi(bw[w]);
    float c0=bflo(cw[w]), c1=bfhi(cw[w]);
    float d0=bflo(dw[w]), d1=bfhi(dw[w]);
    float t0=a0+wx*(b0-a0), u0=c0+wx*(d0-c0);
    float t1=a1+wx*(b1-a1), u1=c1+wx*(d1-c1);
    m[2*w]   = t0 + wy*(u0-t0);
    m[2*w+1] = t1 + wy*(u1-t1);
  }
}

__device__ __forceinline__ void gather8_f32(const float* __restrict__ plane,
                                            int rbase, int y0,int y1,int x0,int x1,
                                            float wx, float wy, float m[8])
{
#pragma unroll
  for (int j=0;j<8;++j){
    const float* mp = plane + (size_t)(rbase+j)*90000;
    float v00 = mp[y0*300+x0], v01 = mp[y0*300+x1];
    float v10 = mp[y1*300+x0], v11 = mp[y1*300+x1];
    float t = v00 + wx*(v01-v00), u = v10 + wx*(v11-v10);
    m[j] = t + wy*(u-t);
  }
}

template<bool TR>
__global__ __launch_bounds__(256, 2)
void main_k(const float* __restrict__ xin,
            const float* __restrict__ Weff, const float* __restrict__ vd,
            const float* __restrict__ W1p,
            const u16* __restrict__ Tc, const u16* __restrict__ Td,
            const float* __restrict__ vmc_mat, const float* __restrict__ vmd_mat,
            const float* __restrict__ b1, const float* __restrict__ w2,
            const float* __restrict__ b2, const float* __restrict__ w3,
            const float* __restrict__ b3, float* __restrict__ out)
{
  __shared__ __align__(16) float X[64*XS];     // mlp_in tile, later reused as H2 (stride 132)
  __shared__ __align__(16) float H1[64*128];

  const int tid = threadIdx.x;
  const int s = tid & 63, p = tid >> 6;        // p is wave index
  const size_t n = (size_t)blockIdx.x*64 + s;

  const float* xp = xin + n*6;
  float p0v = xp[0], p1v = xp[1], p2v = xp[2];
  float d0 = xp[3],  d1 = xp[4],  d2 = xp[5];

  float fpart[27];
#pragma unroll
  for (int f=0; f<27; ++f) fpart[f] = 0.f;

  // ---------- Phase A: plane sampling ----------
  if (p < 3) {
    float cx = (p==0) ? p1v : ((p==1) ? p2v : p0v);
    float cy = (p==0) ? p2v : ((p==1) ? p0v : p1v);
    float fx = (cx + 1.0f)*0.5f*299.0f;
    float fy = (cy + 1.0f)*0.5f*299.0f;
    float x0f = floorf(fx), y0f = floorf(fy);
    int x0 = min(max((int)x0f, 0), 299);
    int y0 = min(max((int)y0f, 0), 299);
    int x1 = min(x0+1, 299), y1 = min(y0+1, 299);
    float wx = fx - x0f, wy = fy - y0f;

    if constexpr (TR) {
      const u16* base = Tc + (size_t)p*90000*48;
      const u16* r00 = base + ((size_t)y0*300 + x0)*48;
      const u16* r01 = base + ((size_t)y0*300 + x1)*48;
      const u16* r10 = base + ((size_t)y1*300 + x0)*48;
      const u16* r11 = base + ((size_t)y1*300 + x1)*48;
#pragma unroll
      for (int cg=0; cg<6; ++cg){
        float m[8];
        lerp8(r00, r01, r10, r11, cg*8, wx, wy, m);
        const float* wb = Weff + p*48 + cg*8;
#pragma unroll
        for (int f=0; f<27; ++f){
          float4 w0 = *(const float4*)(wb + f*144);
          float4 w1v = *(const float4*)(wb + f*144 + 4);
          fpart[f] += m[0]*w0.x + m[1]*w0.y + m[2]*w0.z + m[3]*w0.w
                    + m[4]*w1v.x + m[5]*w1v.y + m[6]*w1v.z + m[7]*w1v.w;
        }
      }
    } else {
      const float* plane = vmc_mat + (size_t)p*48*90000;
#pragma unroll
      for (int cg=0; cg<6; ++cg){
        float m[8];
        gather8_f32(plane, cg*8, y0, y1, x0, x1, wx, wy, m);
        const float* wb = Weff + p*48 + cg*8;
#pragma unroll
        for (int f=0; f<27; ++f){
          float4 w0 = *(const float4*)(wb + f*144);
          float4 w1v = *(const float4*)(wb + f*144 + 4);
          fpart[f] += m[0]*w0.x + m[1]*w0.y + m[2]*w0.z + m[3]*w0.w
                    + m[4]*w1v.x + m[5]*w1v.y + m[6]*w1v.z + m[7]*w1v.w;
        }
      }
    }
  } else {
    // ---------- density wave ----------
    float dacc = 0.f;
#pragma unroll
    for (int i=0; i<3; ++i){
      float cx = (i==0) ? p1v : ((i==1) ? p2v : p0v);
      float cy = (i==0) ? p2v : ((i==1) ? p0v : p1v);
      float fx = (cx + 1.0f)*0.5f*299.0f;
      float fy = (cy + 1.0f)*0.5f*299.0f;
      float x0f = floorf(fx), y0f = floorf(fy);
      int x0 = min(max((int)x0f, 0), 299);
      int y0 = min(max((int)y0f, 0), 299);
      int x1 = min(x0+1, 299), y1 = min(y0+1, 299);
      float wx = fx - x0f, wy = fy - y0f;
      if constexpr (TR) {
        const u16* base = Td + (size_t)i*90000*16;
        const u16* r00 = base + ((size_t)y0*300 + x0)*16;
        const u16* r01 = base + ((size_t)y0*300 + x1)*16;
        const u16* r10 = base + ((size_t)y1*300 + x0)*16;
        const u16* r11 = base + ((size_t)y1*300 + x1)*16;
#pragma unroll
        for (int cg=0; cg<2; ++cg){
          float m[8];
          lerp8(r00, r01, r10, r11, cg*8, wx, wy, m);
          float4 v0 = *(const float4*)(vd + i*16 + cg*8);
          float4 v1 = *(const float4*)(vd + i*16 + cg*8 + 4);
          dacc += m[0]*v0.x + m[1]*v0.y + m[2]*v0.z + m[3]*v0.w
                + m[4]*v1.x + m[5]*v1.y + m[6]*v1.z + m[7]*v1.w;
        }
      } else {
        const float* plane = vmd_mat + (size_t)i*16*90000;
#pragma unroll
        for (int cg=0; cg<2; ++cg){
          float m[8];
          gather8_f32(plane, cg*8, y0, y1, x0, x1, wx, wy, m);
          float4 v0 = *(const float4*)(vd + i*16 + cg*8);
          float4 v1 = *(const float4*)(vd + i*16 + cg*8 + 4);
          dacc += m[0]*v0.x + m[1]*v0.y + m[2]*v0.z + m[3]*v0.w
                + m[4]*v1.x + m[5]*v1.y + m[6]*v1.z + m[7]*v1.w;
        }
      }
    }
    out[n*4 + 3] = fmaxf(dacc, 0.f);
  }

  // ---------- fold partial features ----------
  float* Xr = X + s*XS;
  if (p == 0){
#pragma unroll
    for (int f=0; f<27; ++f) Xr[f] = fpart[f];
    Xr[27] = d0; Xr[28] = d1; Xr[29] = d2;
    Xr[150]=0.f; Xr[151]=0.f; Xr[152]=0.f; Xr[153]=0.f; Xr[154]=0.f; Xr[155]=0.f;
  }
  __syncthreads();
  if (p == 1){
#pragma unroll
    for (int f=0; f<27; ++f) Xr[f] += fpart[f];
  }
  __syncthreads();
  if (p == 2){
#pragma unroll
    for (int f=0; f<27; ++f) Xr[f] += fpart[f];
  }
  __syncthreads();

  // ---------- Phase B: positional encoding ----------
  {
    const float cf = (p & 2) ? 6.283185307179586f : 3.141592653589793f;
#pragma unroll
    for (int j=0; j<27; ++j){
      float f = Xr[j];
      float a = cf * f;
      Xr[30 + p*27 + j] = (p & 1) ? __cosf(a) : __sinf(a);
    }
    float dv[3] = {d0, d1, d2};
#pragma unroll
    for (int d=0; d<3; ++d){
      float a = cf * dv[d];
      Xr[138 + p*3 + d] = (p & 1) ? __cosf(a) : __sinf(a);
    }
  }
  __syncthreads();

  // ---------- Phase C: layer1 150->128 ----------
  const int hg = tid & 31, sg = tid >> 5;
  const int hb = hg*4, sb = sg*8;
  {
    float acc[4][8];
#pragma unroll
    for (int a=0;a<4;++a)
#pragma unroll
      for (int b=0;b<8;++b) acc[a][b]=0.f;
    for (int k=0; k<152; k+=4){
      float4 xv[8];
#pragma unroll
      for (int b=0;b<8;++b) xv[b] = *(const float4*)(X + (sb+b)*XS + k);
#pragma unroll
      for (int a=0;a<4;++a){
        float4 w = *(const float4*)(W1p + (hb+a)*152 + k);
#pragma unroll
        for (int b=0;b<8;++b)
          acc[a][b] += w.x*xv[b].x + w.y*xv[b].y + w.z*xv[b].z + w.w*xv[b].w;
      }
    }
    float bb0=b1[hb+0], bb1=b1[hb+1], bb2=b1[hb+2], bb3=b1[hb+3];
#pragma unroll
    for (int b=0;b<8;++b){
      float4 o;
      o.x = fmaxf(acc[0][b]+bb0, 0.f);
      o.y = fmaxf(acc[1][b]+bb1, 0.f);
      o.z = fmaxf(acc[2][b]+bb2, 0.f);
      o.w = fmaxf(acc[3][b]+bb3, 0.f);
      *(float4*)(H1 + (sb+b)*128 + hb) = o;
    }
  }
  __syncthreads();

  // ---------- Phase D: layer2 128->128 (H2 overlays X, stride 132) ----------
  {
    float acc[4][8];
#pragma unroll
    for (int a=0;a<4;++a)
#pragma unroll
      for (int b=0;b<8;++b) acc[a][b]=0.f;
    for (int k=0; k<128; k+=4){
      float4 xv[8];
#pragma unroll
      for (int b=0;b<8;++b) xv[b] = *(const float4*)(H1 + (sb+b)*128 + k);
#pragma unroll
      for (int a=0;a<4;++a){
        float4 w = *(const float4*)(w2 + (hb+a)*128 + k);
#pragma unroll
        for (int b=0;b<8;++b)
          acc[a][b] += w.x*xv[b].x + w.y*xv[b].y + w.z*xv[b].z + w.w*xv[b].w;
      }
    }
    float bb0=b2[hb+0], bb1=b2[hb+1], bb2v=b2[hb+2], bb3=b2[hb+3];
#pragma unroll
    for (int b=0;b<8;++b){
      float4 o;
      o.x = fmaxf(acc[0][b]+bb0, 0.f);
      o.y = fmaxf(acc[1][b]+bb1, 0.f);
      o.z = fmaxf(acc[2][b]+bb2v, 0.f);
      o.w = fmaxf(acc[3][b]+bb3, 0.f);
      *(float4*)(X + (sb+b)*132 + hb) = o;
    }
  }
  __syncthreads();

  // ---------- Phase E: layer3 + sigmoid ----------
  if (tid < 192){
    int ss = tid / 3, o = tid - ss*3;
    float acc = 0.f;
    for (int k=0; k<128; k+=4){
      float4 h = *(const float4*)(X + ss*132 + k);
      float4 w = *(const float4*)(w3 + o*128 + k);
      acc += h.x*w.x + h.y*w.y + h.z*w.z + h.w*w.w;
    }
    float c = acc + b3[o];
    out[((size_t)blockIdx.x*64 + ss)*4 + o] = 1.f/(1.f + __expf(-c));
  }
}

extern "C" void kernel_launch(void* const* d_in, const int* in_sizes, int n_in,
                              void* d_out, int out_size, void* d_ws, size_t ws_size,
                              hipStream_t stream)
{
  const float* xin     = (const float*)d_in[0];
  const float* vmc_vec = (const float*)d_in[1];
  const float* vmc_mat = (const float*)d_in[2];
  const float* vmd_vec = (const float*)d_in[3];
  const float* vmd_mat = (const float*)d_in[4];
  const float* feat_w  = (const float*)d_in[5];
  const float* w1      = (const float*)d_in[6];
  const float* b1      = (const float*)d_in[7];
  const float* w2      = (const float*)d_in[8];
  const float* b2      = (const float*)d_in[9];
  const float* w3      = (const float*)d_in[10];
  const float* b3      = (const float*)d_in[11];
  float* out = (float*)d_out;

  char* ws = (char*)d_ws;
  float* Weff = (float*)(ws + WOFF_WEFF);
  float* vd   = (float*)(ws + WOFF_VD);
  float* W1p  = (float*)(ws + WOFF_W1P);
  u16*   Tc   = (u16*)(ws + WOFF_TC);
  u16*   Td   = (u16*)(ws + WOFF_TD);

  prep_k<<<64, 256, 0, stream>>>(feat_w, vmc_vec, vmd_vec, w1, Weff, vd, W1p);

  if (ws_size >= (size_t)WS_FULL) {
    transpose_k<<<900, 256, 0, stream>>>(vmc_mat, Tc, 48);
    transpose_k<<<900, 256, 0, stream>>>(vmd_mat, Td, 16);
    main_k<true><<<8192, 256, 0, stream>>>(xin, Weff, vd, W1p, Tc, Td,
                                           vmc_mat, vmd_mat, b1, w2, b2, w3, b3, out);
  } else {
    main_k<false><<<8192, 256, 0, stream>>>(xin, Weff, vd, W1p, nullptr, nullptr,
                                            vmc_mat, vmd_mat, b1, w2, b2, w3, b3, out);
  }
}

// Round 2
// 332.750 us; speedup vs baseline: 4.5904x; 4.5904x over previous
//
#include <hip/hip_runtime.h>
#include <stdint.h>

typedef unsigned int u32;
typedef _Float16 f16;
typedef __attribute__((ext_vector_type(8))) _Float16 f16x8;
typedef __attribute__((ext_vector_type(4))) float f32x4;

#define XMS 168   // f16 stride for Xm / X rows (336B = 21*16B, bank-spread)
#define HS  136   // f16 stride for H1 / H2 rows (272B = 17*16B)

// ---- workspace layout (bytes) ----
#define WOFF_WEFF 0u          // 5*32*32*2    = 10240
#define WOFF_W1SW 10240u      // 5*128*32*2   = 40960
#define WOFF_W2SW 51200u      // 4*128*32*2   = 32768
#define WOFF_W3SW 83968u      // 4*16*32*2    = 4096
#define WOFF_VD   88064u      // 48*4         = 192
#define WOFF_TC   131072u     // 3*300*300*48*2 = 25920000
#define WOFF_TD   26051072u   // 3*300*300*16*2 = 8640000
#define WS_NEED   34691072u

// ================= prep: swizzled f16 weights =================
// layout for MFMA B-frags: W[kb][n][kk], kk=0..31 contiguous
__global__ void prep_k(const float* __restrict__ feat_w,
                       const float* __restrict__ vmc_vec,
                       const float* __restrict__ vmd_vec,
                       const float* __restrict__ w1,
                       const float* __restrict__ w2,
                       const float* __restrict__ w3,
                       f16* __restrict__ Weff, f16* __restrict__ W1sw,
                       f16* __restrict__ W2sw, f16* __restrict__ W3sw,
                       float* __restrict__ vd)
{
  const int N_WEFF = 5120, N_W1 = 20480, N_W2 = 16384, N_W3 = 2048, N_VD = 48;
  const int total = N_WEFF + N_W1 + N_W2 + N_W3 + N_VD;
  for (int t = blockIdx.x*blockDim.x + threadIdx.x; t < total; t += gridDim.x*blockDim.x){
    if (t < N_WEFF){
      int kb = t >> 10, n = (t >> 5) & 31, kk = t & 31, k = kb*32 + kk;
      float v = 0.f;
      if (n < 27 && k < 144)
        v = feat_w[n*144 + k] * 0.5f*(vmc_vec[k*300+149] + vmc_vec[k*300+150]);
      Weff[t] = (f16)v;
    } else if (t < N_WEFF + N_W1){
      int u = t - N_WEFF;
      int kb = u >> 12, n = (u >> 5) & 127, kk = u & 31, k = kb*32 + kk;
      W1sw[u] = (f16)((k < 150) ? w1[n*150 + k] : 0.f);
    } else if (t < N_WEFF + N_W1 + N_W2){
      int u = t - N_WEFF - N_W1;
      int kb = u >> 12, n = (u >> 5) & 127, kk = u & 31, k = kb*32 + kk;
      W2sw[u] = (f16)w2[n*128 + k];
    } else if (t < N_WEFF + N_W1 + N_W2 + N_W3){
      int u = t - N_WEFF - N_W1 - N_W2;
      int kb = u >> 9, n = (u >> 5) & 15, kk = u & 31, k = kb*32 + kk;
      W3sw[u] = (f16)((n < 3) ? w3[n*128 + k] : 0.f);
    } else {
      int k = t - N_WEFF - N_W1 - N_W2 - N_W3;
      vd[k] = 0.5f*(vmd_vec[k*300+149] + vmd_vec[k*300+150]);
    }
  }
}

// ---- transpose (3,C,300,300) f32 -> (3,300,300,C) f16 ----
__global__ void transpose_k(const float* __restrict__ src, f16* __restrict__ dst, int C)
{
  __shared__ float tile[48*301];
  int i = blockIdx.x / 300, y = blockIdx.x % 300;
  const float* sp = src + (size_t)i*C*90000 + (size_t)y*300;
  for (int t = threadIdx.x; t < C*300; t += 256) {
    int r = t / 300, xx = t - r*300;
    tile[r*301 + xx] = sp[(size_t)r*90000 + xx];
  }
  __syncthreads();
  f16* dp = dst + (size_t)(i*300 + y)*300*C;
  for (int t = threadIdx.x; t < 300*C; t += 256) {
    int xx = t / C, r = t - xx*C;
    dp[t] = (f16)tile[r*301 + xx];
  }
}

// ================= main fused kernel =================
template<bool TR>
__global__ __launch_bounds__(256, 3)
void main_k(const float* __restrict__ xin,
            const f16* __restrict__ WeffSw, const f16* __restrict__ W1sw,
            const f16* __restrict__ W2sw, const f16* __restrict__ W3sw,
            const float* __restrict__ vd,
            const f16* __restrict__ Tc, const f16* __restrict__ Td,
            const float* __restrict__ vmc_mat, const float* __restrict__ vmd_mat,
            const float* __restrict__ b1v, const float* __restrict__ b2v,
            const float* __restrict__ b3v, float* __restrict__ out)
{
  // bufA: Xm (lerped m, [64][XMS]) then H1 ([64][HS])
  // bufB: X (mlp_in, [64][XMS]) then H2 ([64][HS])
  __shared__ __align__(16) f16 bufA[64*XMS];
  __shared__ __align__(16) f16 bufB[64*XMS];

  const int tid = threadIdx.x;
  const int l = tid & 63;
  const int w = tid >> 6;
  const size_t nidx = (size_t)blockIdx.x*64 + l;

  const float* xp = xin + nidx*6;
  float p0 = xp[0], p1 = xp[1], p2 = xp[2];
  float d0 = xp[3], d1 = xp[4], d2 = xp[5];

  // ---------------- Phase A: sampling ----------------
  if (w < 3){
    float cx = (w==0)? p1 : ((w==1)? p2 : p0);
    float cy = (w==0)? p2 : ((w==1)? p0 : p1);
    float fx = (cx+1.f)*0.5f*299.f, fy = (cy+1.f)*0.5f*299.f;
    float x0f = floorf(fx), y0f = floorf(fy);
    int x0 = min(max((int)x0f,0),299), y0 = min(max((int)y0f,0),299);
    int x1 = min(x0+1,299), y1 = min(y0+1,299);
    float wx = fx-x0f, wy = fy-y0f;
    f16* dstrow = bufA + l*XMS + w*48;
    if constexpr (TR){
      const f16* base = Tc + (size_t)w*90000*48;
      const f16* r00 = base + (size_t)(y0*300+x0)*48;
      const f16* r01 = base + (size_t)(y0*300+x1)*48;
      const f16* r10 = base + (size_t)(y1*300+x0)*48;
      const f16* r11 = base + (size_t)(y1*300+x1)*48;
#pragma unroll
      for (int cg=0; cg<6; ++cg){
        f16x8 A = *(const f16x8*)(r00+cg*8);
        f16x8 B = *(const f16x8*)(r01+cg*8);
        f16x8 Cg= *(const f16x8*)(r10+cg*8);
        f16x8 D = *(const f16x8*)(r11+cg*8);
        f16x8 o;
#pragma unroll
        for (int j=0;j<8;++j){
          float a=(float)A[j], b=(float)B[j], c=(float)Cg[j], d=(float)D[j];
          float t=a+wx*(b-a), u=c+wx*(d-c);
          o[j] = (f16)(t + wy*(u-t));
        }
        *(f16x8*)(dstrow + cg*8) = o;
      }
    } else {
      const float* plane = vmc_mat + (size_t)w*48*90000;
#pragma unroll
      for (int cg=0; cg<6; ++cg){
        f16x8 o;
#pragma unroll
        for (int j=0;j<8;++j){
          const float* mp = plane + (size_t)(cg*8+j)*90000;
          float a = mp[y0*300+x0], b = mp[y0*300+x1];
          float c = mp[y1*300+x0], d = mp[y1*300+x1];
          float t=a+wx*(b-a), u=c+wx*(d-c);
          o[j] = (f16)(t + wy*(u-t));
        }
        *(f16x8*)(dstrow + cg*8) = o;
      }
    }
  } else {
    // density wave
    float dacc = 0.f;
#pragma unroll
    for (int i=0;i<3;++i){
      float cx = (i==0)? p1 : ((i==1)? p2 : p0);
      float cy = (i==0)? p2 : ((i==1)? p0 : p1);
      float fx = (cx+1.f)*0.5f*299.f, fy = (cy+1.f)*0.5f*299.f;
      float x0f = floorf(fx), y0f = floorf(fy);
      int x0 = min(max((int)x0f,0),299), y0 = min(max((int)y0f,0),299);
      int x1 = min(x0+1,299), y1 = min(y0+1,299);
      float wx = fx-x0f, wy = fy-y0f;
      if constexpr (TR){
        const f16* base = Td + (size_t)i*90000*16;
        const f16* r00 = base + (size_t)(y0*300+x0)*16;
        const f16* r01 = base + (size_t)(y0*300+x1)*16;
        const f16* r10 = base + (size_t)(y1*300+x0)*16;
        const f16* r11 = base + (size_t)(y1*300+x1)*16;
#pragma unroll
        for (int cg=0; cg<2; ++cg){
          f16x8 A = *(const f16x8*)(r00+cg*8);
          f16x8 B = *(const f16x8*)(r01+cg*8);
          f16x8 Cg= *(const f16x8*)(r10+cg*8);
          f16x8 D = *(const f16x8*)(r11+cg*8);
#pragma unroll
          for (int j=0;j<8;++j){
            float a=(float)A[j], b=(float)B[j], c=(float)Cg[j], d=(float)D[j];
            float t=a+wx*(b-a), u=c+wx*(d-c);
            dacc += (t + wy*(u-t)) * vd[i*16 + cg*8 + j];
          }
        }
      } else {
        const float* plane = vmd_mat + (size_t)i*16*90000;
#pragma unroll
        for (int cg=0; cg<2; ++cg){
#pragma unroll
          for (int j=0;j<8;++j){
            const float* mp = plane + (size_t)(cg*8+j)*90000;
            float a = mp[y0*300+x0], b = mp[y0*300+x1];
            float c = mp[y1*300+x0], d = mp[y1*300+x1];
            float t=a+wx*(b-a), u=c+wx*(d-c);
            dacc += (t + wy*(u-t)) * vd[i*16 + cg*8 + j];
          }
        }
      }
    }
    out[nidx*4 + 3] = fmaxf(dacc, 0.f);
    // zero Xm K-pad [144..160)
    f16x8 z = 0;
    *(f16x8*)(bufA + l*XMS + 144) = z;
    *(f16x8*)(bufA + l*XMS + 152) = z;
  }
  __syncthreads();

  const int tr = l & 15;          // within-tile row/col
  const int ko = (l >> 4) * 8;    // k-suboffset (8 f16 per lane)

  // ---------------- Phase B: fold MFMA (64x160 * 160x32) + PE ----------------
  {
    f32x4 fa0 = {0.f,0.f,0.f,0.f}, fa1 = {0.f,0.f,0.f,0.f};
    const f16* Arow = bufA + (w*16 + tr)*XMS + ko;
#pragma unroll
    for (int kb=0; kb<5; ++kb){
      f16x8 a  = *(const f16x8*)(Arow + kb*32);
      f16x8 b0 = *(const f16x8*)(WeffSw + (size_t)(kb*32 + tr)*32 + ko);
      f16x8 b1 = *(const f16x8*)(WeffSw + (size_t)(kb*32 + 16 + tr)*32 + ko);
      fa0 = __builtin_amdgcn_mfma_f32_16x16x32_f16(a, b0, fa0, 0,0,0);
      fa1 = __builtin_amdgcn_mfma_f32_16x16x32_f16(a, b1, fa1, 0,0,0);
    }
    const int sbase = w*16 + (l>>4)*4;
#pragma unroll
    for (int nb=0; nb<2; ++nb){
      int f = nb*16 + tr;
      if (f < 27){
#pragma unroll
        for (int r=0;r<4;++r){
          float fv = nb ? fa1[r] : fa0[r];
          f16* Xr = bufB + (sbase + r)*XMS;
          Xr[f] = (f16)fv;
          float a1 = 3.14159265358979f*fv;
          float a2 = 6.28318530717959f*fv;
          Xr[30+f]  = (f16)__sinf(a1);
          Xr[57+f]  = (f16)__cosf(a1);
          Xr[84+f]  = (f16)__sinf(a2);
          Xr[111+f] = (f16)__cosf(a2);
        }
      }
    }
    if (w == 0){
      f16* Xr = bufB + l*XMS;
      Xr[27]=(f16)d0; Xr[28]=(f16)d1; Xr[29]=(f16)d2;
      float dv[3]={d0,d1,d2};
#pragma unroll
      for (int j=0;j<3;++j){
        float a1=3.14159265358979f*dv[j], a2=6.28318530717959f*dv[j];
        Xr[138+j]=(f16)__sinf(a1);
        Xr[141+j]=(f16)__cosf(a1);
        Xr[144+j]=(f16)__sinf(a2);
        Xr[147+j]=(f16)__cosf(a2);
      }
#pragma unroll
      for (int j=150;j<160;++j) Xr[j]=(f16)0.f;
    }
  }
  __syncthreads();

  // ---------------- Phase C: layer1 (64x160 * 160x128) ----------------
  {
    f32x4 acc[4][2];
#pragma unroll
    for (int m=0;m<4;++m){ acc[m][0]=(f32x4){0.f,0.f,0.f,0.f}; acc[m][1]=(f32x4){0.f,0.f,0.f,0.f}; }
    const int n0 = w*32 + tr;
#pragma unroll
    for (int kb=0; kb<5; ++kb){
      f16x8 b0 = *(const f16x8*)(W1sw + (size_t)(kb*128 + n0)*32 + ko);
      f16x8 b1 = *(const f16x8*)(W1sw + (size_t)(kb*128 + n0 + 16)*32 + ko);
#pragma unroll
      for (int m=0;m<4;++m){
        f16x8 a = *(const f16x8*)(bufB + (m*16 + tr)*XMS + kb*32 + ko);
        acc[m][0] = __builtin_amdgcn_mfma_f32_16x16x32_f16(a, b0, acc[m][0], 0,0,0);
        acc[m][1] = __builtin_amdgcn_mfma_f32_16x16x32_f16(a, b1, acc[m][1], 0,0,0);
      }
    }
    float bb0 = b1v[n0], bb1 = b1v[n0+16];
    f16* H1 = bufA;
#pragma unroll
    for (int m=0;m<4;++m){
#pragma unroll
      for (int r=0;r<4;++r){
        int ss = m*16 + (l>>4)*4 + r;
        H1[ss*HS + n0]      = (f16)fmaxf(acc[m][0][r] + bb0, 0.f);
        H1[ss*HS + n0 + 16] = (f16)fmaxf(acc[m][1][r] + bb1, 0.f);
      }
    }
  }
  __syncthreads();

  // ---------------- Phase D: layer2 (64x128 * 128x128) ----------------
  {
    f32x4 acc[4][2];
#pragma unroll
    for (int m=0;m<4;++m){ acc[m][0]=(f32x4){0.f,0.f,0.f,0.f}; acc[m][1]=(f32x4){0.f,0.f,0.f,0.f}; }
    const int n0 = w*32 + tr;
    const f16* H1 = bufA;
#pragma unroll
    for (int kb=0; kb<4; ++kb){
      f16x8 b0 = *(const f16x8*)(W2sw + (size_t)(kb*128 + n0)*32 + ko);
      f16x8 b1 = *(const f16x8*)(W2sw + (size_t)(kb*128 + n0 + 16)*32 + ko);
#pragma unroll
      for (int m=0;m<4;++m){
        f16x8 a = *(const f16x8*)(H1 + (m*16 + tr)*HS + kb*32 + ko);
        acc[m][0] = __builtin_amdgcn_mfma_f32_16x16x32_f16(a, b0, acc[m][0], 0,0,0);
        acc[m][1] = __builtin_amdgcn_mfma_f32_16x16x32_f16(a, b1, acc[m][1], 0,0,0);
      }
    }
    float bb0 = b2v[n0], bb1 = b2v[n0+16];
    f16* H2 = bufB;
#pragma unroll
    for (int m=0;m<4;++m){
#pragma unroll
      for (int r=0;r<4;++r){
        int ss = m*16 + (l>>4)*4 + r;
        H2[ss*HS + n0]      = (f16)fmaxf(acc[m][0][r] + bb0, 0.f);
        H2[ss*HS + n0 + 16] = (f16)fmaxf(acc[m][1][r] + bb1, 0.f);
      }
    }
  }
  __syncthreads();

  // ---------------- Phase E: layer3 + sigmoid ----------------
  {
    f32x4 acc = {0.f,0.f,0.f,0.f};
    const f16* H2 = bufB;
#pragma unroll
    for (int kb=0; kb<4; ++kb){
      f16x8 a = *(const f16x8*)(H2 + (w*16 + tr)*HS + kb*32 + ko);
      f16x8 b = *(const f16x8*)(W3sw + (size_t)(kb*16 + tr)*32 + ko);
      acc = __builtin_amdgcn_mfma_f32_16x16x32_f16(a, b, acc, 0,0,0);
    }
    if (tr < 3){
      float bb = b3v[tr];
#pragma unroll
      for (int r=0;r<4;++r){
        int ss = w*16 + (l>>4)*4 + r;
        float c = acc[r] + bb;
        out[((size_t)blockIdx.x*64 + ss)*4 + tr] = 1.f/(1.f + __expf(-c));
      }
    }
  }
}

extern "C" void kernel_launch(void* const* d_in, const int* in_sizes, int n_in,
                              void* d_out, int out_size, void* d_ws, size_t ws_size,
                              hipStream_t stream)
{
  const float* xin     = (const float*)d_in[0];
  const float* vmc_vec = (const float*)d_in[1];
  const float* vmc_mat = (const float*)d_in[2];
  const float* vmd_vec = (const float*)d_in[3];
  const float* vmd_mat = (const float*)d_in[4];
  const float* feat_w  = (const float*)d_in[5];
  const float* w1      = (const float*)d_in[6];
  const float* b1      = (const float*)d_in[7];
  const float* w2      = (const float*)d_in[8];
  const float* b2      = (const float*)d_in[9];
  const float* w3      = (const float*)d_in[10];
  const float* b3      = (const float*)d_in[11];
  float* out = (float*)d_out;

  char* ws = (char*)d_ws;
  f16*   Weff = (f16*)(ws + WOFF_WEFF);
  f16*   W1sw = (f16*)(ws + WOFF_W1SW);
  f16*   W2sw = (f16*)(ws + WOFF_W2SW);
  f16*   W3sw = (f16*)(ws + WOFF_W3SW);
  float* vd   = (float*)(ws + WOFF_VD);
  f16*   Tc   = (f16*)(ws + WOFF_TC);
  f16*   Td   = (f16*)(ws + WOFF_TD);

  prep_k<<<64, 256, 0, stream>>>(feat_w, vmc_vec, vmd_vec, w1, w2, w3,
                                 Weff, W1sw, W2sw, W3sw, vd);

  if (ws_size >= (size_t)WS_NEED) {
    transpose_k<<<900, 256, 0, stream>>>(vmc_mat, Tc, 48);
    transpose_k<<<900, 256, 0, stream>>>(vmd_mat, Td, 16);
    main_k<true><<<8192, 256, 0, stream>>>(xin, Weff, W1sw, W2sw, W3sw, vd, Tc, Td,
                                           vmc_mat, vmd_mat, b1, b2, b3, out);
  } else {
    main_k<false><<<8192, 256, 0, stream>>>(xin, Weff, W1sw, W2sw, W3sw, vd, nullptr, nullptr,
                                            vmc_mat, vmd_mat, b1, b2, b3, out);
  }
}

// Round 3
// 222.194 us; speedup vs baseline: 6.8745x; 1.4976x over previous
//
#include <hip/hip_runtime.h>
#include <stdint.h>

typedef unsigned int u32;
typedef _Float16 f16;
typedef __attribute__((ext_vector_type(8))) _Float16 f16x8;
typedef __attribute__((ext_vector_type(4))) float f32x4;
typedef __attribute__((ext_vector_type(2))) float f32x2;

#define XMS 168   // f16 stride for Xm / X rows
#define HS  136   // f16 stride for H1 / H2 rows

// ---- workspace layout (bytes) ----
#define WOFF_WEFF 0u          // 5*32*32*2    = 10240
#define WOFF_W1SW 10240u      // 5*128*32*2   = 40960
#define WOFF_W2SW 51200u      // 4*128*32*2   = 32768
#define WOFF_W3SW 83968u      // 4*16*32*2    = 4096
#define WOFF_VD   88064u      // 48*4         = 192
#define WOFF_TM   131072u     // 3*300*300*64 = 17280000 (fp8)
#define WS_NEED   17411072u

#define TBL_SCALE 64.0f
#define TBL_INV   (1.0f/64.0f)

// ================= prep: swizzled f16 weights (1/64 folded) =================
__global__ void prep_k(const float* __restrict__ feat_w,
                       const float* __restrict__ vmc_vec,
                       const float* __restrict__ vmd_vec,
                       const float* __restrict__ w1,
                       const float* __restrict__ w2,
                       const float* __restrict__ w3,
                       f16* __restrict__ Weff, f16* __restrict__ W1sw,
                       f16* __restrict__ W2sw, f16* __restrict__ W3sw,
                       float* __restrict__ vd)
{
  const int N_WEFF = 5120, N_W1 = 20480, N_W2 = 16384, N_W3 = 2048, N_VD = 48;
  const int total = N_WEFF + N_W1 + N_W2 + N_W3 + N_VD;
  for (int t = blockIdx.x*blockDim.x + threadIdx.x; t < total; t += gridDim.x*blockDim.x){
    if (t < N_WEFF){
      int kb = t >> 10, n = (t >> 5) & 31, kk = t & 31, k = kb*32 + kk;
      float v = 0.f;
      if (n < 27 && k < 144)
        v = feat_w[n*144 + k] * 0.5f*(vmc_vec[k*300+149] + vmc_vec[k*300+150]) * TBL_INV;
      Weff[t] = (f16)v;
    } else if (t < N_WEFF + N_W1){
      int u = t - N_WEFF;
      int kb = u >> 12, n = (u >> 5) & 127, kk = u & 31, k = kb*32 + kk;
      W1sw[u] = (f16)((k < 150) ? w1[n*150 + k] : 0.f);
    } else if (t < N_WEFF + N_W1 + N_W2){
      int u = t - N_WEFF - N_W1;
      int kb = u >> 12, n = (u >> 5) & 127, kk = u & 31, k = kb*32 + kk;
      W2sw[u] = (f16)w2[n*128 + k];
    } else if (t < N_WEFF + N_W1 + N_W2 + N_W3){
      int u = t - N_WEFF - N_W1 - N_W2;
      int kb = u >> 9, n = (u >> 5) & 15, kk = u & 31, k = kb*32 + kk;
      W3sw[u] = (f16)((n < 3) ? w3[n*128 + k] : 0.f);
    } else {
      int k = t - N_WEFF - N_W1 - N_W2 - N_W3;
      vd[k] = 0.5f*(vmd_vec[k*300+149] + vmd_vec[k*300+150]) * TBL_INV;
    }
  }
}

// ---- pack feature channels: (3,48,300,300) f32 -> Tm[...][ch 0..47] fp8*64 ----
__global__ void pack_feat_k(const float* __restrict__ src, u32* __restrict__ dst)
{
  __shared__ float tile[48*304];
  int i = blockIdx.x / 300, y = blockIdx.x % 300;
  const float* sp = src + (size_t)i*48*90000 + (size_t)y*300;
  for (int t = threadIdx.x; t < 48*300; t += 256){
    int r = t / 300, x = t - r*300;
    tile[r*304 + x] = sp[(size_t)r*90000 + x] * TBL_SCALE;
  }
  __syncthreads();
  u32* dp = dst + (size_t)(i*300 + y)*300*16;
  for (int t = threadIdx.x; t < 300*12; t += 256){
    int x = t / 12, cg = t - x*12;
    int c = cg*4;
    u32 v = __builtin_amdgcn_cvt_pk_fp8_f32(tile[c*304+x],     tile[(c+1)*304+x], 0, false);
    v     = __builtin_amdgcn_cvt_pk_fp8_f32(tile[(c+2)*304+x], tile[(c+3)*304+x], v, true);
    dp[x*16 + cg] = v;
  }
}

// ---- pack density channels: (3,16,300,300) f32 -> Tm[...][ch 48..63] fp8*64 ----
__global__ void pack_dens_k(const float* __restrict__ src, u32* __restrict__ dst)
{
  __shared__ float tile[16*304];
  int i = blockIdx.x / 300, y = blockIdx.x % 300;
  const float* sp = src + (size_t)i*16*90000 + (size_t)y*300;
  for (int t = threadIdx.x; t < 16*300; t += 256){
    int r = t / 300, x = t - r*300;
    tile[r*304 + x] = sp[(size_t)r*90000 + x] * TBL_SCALE;
  }
  __syncthreads();
  u32* dp = dst + (size_t)(i*300 + y)*300*16;
  for (int t = threadIdx.x; t < 300*4; t += 256){
    int x = t / 4, cg = t - x*4;
    int c = cg*4;
    u32 v = __builtin_amdgcn_cvt_pk_fp8_f32(tile[c*304+x],     tile[(c+1)*304+x], 0, false);
    v     = __builtin_amdgcn_cvt_pk_fp8_f32(tile[(c+2)*304+x], tile[(c+3)*304+x], v, true);
    dp[x*16 + 12 + cg] = v;
  }
}

__device__ __forceinline__ void decode16(uint4 q, float* o){
  f32x2 t;
  t = __builtin_amdgcn_cvt_pk_f32_fp8(q.x, false); o[0]=t[0];  o[1]=t[1];
  t = __builtin_amdgcn_cvt_pk_f32_fp8(q.x, true ); o[2]=t[0];  o[3]=t[1];
  t = __builtin_amdgcn_cvt_pk_f32_fp8(q.y, false); o[4]=t[0];  o[5]=t[1];
  t = __builtin_amdgcn_cvt_pk_f32_fp8(q.y, true ); o[6]=t[0];  o[7]=t[1];
  t = __builtin_amdgcn_cvt_pk_f32_fp8(q.z, false); o[8]=t[0];  o[9]=t[1];
  t = __builtin_amdgcn_cvt_pk_f32_fp8(q.z, true ); o[10]=t[0]; o[11]=t[1];
  t = __builtin_amdgcn_cvt_pk_f32_fp8(q.w, false); o[12]=t[0]; o[13]=t[1];
  t = __builtin_amdgcn_cvt_pk_f32_fp8(q.w, true ); o[14]=t[0]; o[15]=t[1];
}

// ================= main fused kernel =================
__global__ __launch_bounds__(256, 3)
void main_k(const float* __restrict__ xin,
            const f16* __restrict__ WeffSw, const f16* __restrict__ W1sw,
            const f16* __restrict__ W2sw, const f16* __restrict__ W3sw,
            const float* __restrict__ vd,
            const uint4* __restrict__ Tm,
            const float* __restrict__ b1v, const float* __restrict__ b2v,
            const float* __restrict__ b3v, float* __restrict__ out)
{
  __shared__ __align__(16) f16 bufA[64*XMS];   // Xm, then H1
  __shared__ __align__(16) f16 bufB[64*XMS];   // X (mlp_in), then H2
  __shared__ float dLds[192];

  const int tid = threadIdx.x;
  const int l = tid & 63;
  const int w = tid >> 6;
  const size_t nidx = (size_t)blockIdx.x*64 + l;

  const float* xp = xin + nidx*6;
  float p0 = xp[0], p1 = xp[1], p2 = xp[2];
  float d0 = xp[3], d1 = xp[4], d2 = xp[5];

  // ---------------- Phase A: sampling (waves 0..2, one plane each) ----------------
  if (w < 3){
    float cx = (w==0)? p1 : ((w==1)? p2 : p0);
    float cy = (w==0)? p2 : ((w==1)? p0 : p1);
    float fx = (cx+1.f)*0.5f*299.f, fy = (cy+1.f)*0.5f*299.f;
    float x0f = floorf(fx), y0f = floorf(fy);
    int x0 = min(max((int)x0f,0),299), y0 = min(max((int)y0f,0),299);
    int x1 = min(x0+1,299), y1 = min(y0+1,299);
    float wx = fx-x0f, wy = fy-y0f;
    float w11 = wx*wy, w10 = wy - w11, w01 = wx - w11, w00 = 1.f - wx - wy + w11;

    const uint4* Tb = Tm + (size_t)w*90000*4;
    const uint4* r00 = Tb + (size_t)(y0*300+x0)*4;
    const uint4* r01 = Tb + (size_t)(y0*300+x1)*4;
    const uint4* r10 = Tb + (size_t)(y1*300+x0)*4;
    const uint4* r11 = Tb + (size_t)(y1*300+x1)*4;
    uint4 qa[4], qb[4], qc[4], qd[4];
#pragma unroll
    for (int c4=0;c4<4;++c4){ qa[c4]=r00[c4]; qb[c4]=r01[c4]; qc[c4]=r10[c4]; qd[c4]=r11[c4]; }

    float vdw[16];
#pragma unroll
    for (int j=0;j<16;++j) vdw[j] = vd[w*16 + j];

    f16* dstrow = bufA + l*XMS + w*48;
    float dacc = 0.f;
#pragma unroll
    for (int c4=0;c4<4;++c4){
      float A[16],B[16],C[16],D[16];
      decode16(qa[c4],A); decode16(qb[c4],B); decode16(qc[c4],C); decode16(qd[c4],D);
      if (c4 < 3){
        f16x8 o0, o1;
#pragma unroll
        for (int j=0;j<8;++j)
          o0[j] = (f16)(w00*A[j] + w01*B[j] + w10*C[j] + w11*D[j]);
#pragma unroll
        for (int j=0;j<8;++j)
          o1[j] = (f16)(w00*A[8+j] + w01*B[8+j] + w10*C[8+j] + w11*D[8+j]);
        *(f16x8*)(dstrow + c4*16)     = o0;
        *(f16x8*)(dstrow + c4*16 + 8) = o1;
      } else {
#pragma unroll
        for (int j=0;j<16;++j)
          dacc += (w00*A[j] + w01*B[j] + w10*C[j] + w11*D[j]) * vdw[j];
      }
    }
    dLds[w*64 + l] = dacc;
  } else {
    // wave 3: zero Xm K-pad [144..160)
    f16x8 z = 0;
    *(f16x8*)(bufA + l*XMS + 144) = z;
    *(f16x8*)(bufA + l*XMS + 152) = z;
  }
  __syncthreads();

  const int tr = l & 15;          // within-tile row/col
  const int ko = (l >> 4) * 8;    // k-suboffset (8 f16 per lane)

  // ---------------- Phase B: fold MFMA (64x160 * 160x32) + PE ----------------
  {
    if (w == 3){
      float ds = dLds[l] + dLds[64 + l] + dLds[128 + l];
      out[nidx*4 + 3] = fmaxf(ds, 0.f);
    }
    f32x4 fa0 = {0.f,0.f,0.f,0.f}, fa1 = {0.f,0.f,0.f,0.f};
    const f16* Arow = bufA + (w*16 + tr)*XMS + ko;
#pragma unroll
    for (int kb=0; kb<5; ++kb){
      f16x8 a  = *(const f16x8*)(Arow + kb*32);
      f16x8 b0 = *(const f16x8*)(WeffSw + (size_t)(kb*32 + tr)*32 + ko);
      f16x8 b1 = *(const f16x8*)(WeffSw + (size_t)(kb*32 + 16 + tr)*32 + ko);
      fa0 = __builtin_amdgcn_mfma_f32_16x16x32_f16(a, b0, fa0, 0,0,0);
      fa1 = __builtin_amdgcn_mfma_f32_16x16x32_f16(a, b1, fa1, 0,0,0);
    }
    const int sbase = w*16 + (l>>4)*4;
#pragma unroll
    for (int nb=0; nb<2; ++nb){
      int f = nb*16 + tr;
      if (f < 27){
#pragma unroll
        for (int r=0;r<4;++r){
          float fv = nb ? fa1[r] : fa0[r];
          f16* Xr = bufB + (sbase + r)*XMS;
          Xr[f] = (f16)fv;
          float a1 = 3.14159265358979f*fv;
          float a2 = 6.28318530717959f*fv;
          Xr[30+f]  = (f16)__sinf(a1);
          Xr[57+f]  = (f16)__cosf(a1);
          Xr[84+f]  = (f16)__sinf(a2);
          Xr[111+f] = (f16)__cosf(a2);
        }
      }
    }
    if (w == 0){
      f16* Xr = bufB + l*XMS;
      Xr[27]=(f16)d0; Xr[28]=(f16)d1; Xr[29]=(f16)d2;
      float dv[3]={d0,d1,d2};
#pragma unroll
      for (int j=0;j<3;++j){
        float a1=3.14159265358979f*dv[j], a2=6.28318530717959f*dv[j];
        Xr[138+j]=(f16)__sinf(a1);
        Xr[141+j]=(f16)__cosf(a1);
        Xr[144+j]=(f16)__sinf(a2);
        Xr[147+j]=(f16)__cosf(a2);
      }
#pragma unroll
      for (int j=150;j<160;++j) Xr[j]=(f16)0.f;
    }
  }
  __syncthreads();

  // ---------------- Phase C: layer1 (64x160 * 160x128) ----------------
  {
    f32x4 acc[4][2];
#pragma unroll
    for (int m=0;m<4;++m){ acc[m][0]=(f32x4){0.f,0.f,0.f,0.f}; acc[m][1]=(f32x4){0.f,0.f,0.f,0.f}; }
    const int n0 = w*32 + tr;
#pragma unroll
    for (int kb=0; kb<5; ++kb){
      f16x8 b0 = *(const f16x8*)(W1sw + (size_t)(kb*128 + n0)*32 + ko);
      f16x8 b1 = *(const f16x8*)(W1sw + (size_t)(kb*128 + n0 + 16)*32 + ko);
#pragma unroll
      for (int m=0;m<4;++m){
        f16x8 a = *(const f16x8*)(bufB + (m*16 + tr)*XMS + kb*32 + ko);
        acc[m][0] = __builtin_amdgcn_mfma_f32_16x16x32_f16(a, b0, acc[m][0], 0,0,0);
        acc[m][1] = __builtin_amdgcn_mfma_f32_16x16x32_f16(a, b1, acc[m][1], 0,0,0);
      }
    }
    float bb0 = b1v[n0], bb1 = b1v[n0+16];
    f16* H1 = bufA;
#pragma unroll
    for (int m=0;m<4;++m){
#pragma unroll
      for (int r=0;r<4;++r){
        int ss = m*16 + (l>>4)*4 + r;
        H1[ss*HS + n0]      = (f16)fmaxf(acc[m][0][r] + bb0, 0.f);
        H1[ss*HS + n0 + 16] = (f16)fmaxf(acc[m][1][r] + bb1, 0.f);
      }
    }
  }
  __syncthreads();

  // ---------------- Phase D: layer2 (64x128 * 128x128) ----------------
  {
    f32x4 acc[4][2];
#pragma unroll
    for (int m=0;m<4;++m){ acc[m][0]=(f32x4){0.f,0.f,0.f,0.f}; acc[m][1]=(f32x4){0.f,0.f,0.f,0.f}; }
    const int n0 = w*32 + tr;
    const f16* H1 = bufA;
#pragma unroll
    for (int kb=0; kb<4; ++kb){
      f16x8 b0 = *(const f16x8*)(W2sw + (size_t)(kb*128 + n0)*32 + ko);
      f16x8 b1 = *(const f16x8*)(W2sw + (size_t)(kb*128 + n0 + 16)*32 + ko);
#pragma unroll
      for (int m=0;m<4;++m){
        f16x8 a = *(const f16x8*)(H1 + (m*16 + tr)*HS + kb*32 + ko);
        acc[m][0] = __builtin_amdgcn_mfma_f32_16x16x32_f16(a, b0, acc[m][0], 0,0,0);
        acc[m][1] = __builtin_amdgcn_mfma_f32_16x16x32_f16(a, b1, acc[m][1], 0,0,0);
      }
    }
    float bb0 = b2v[n0], bb1 = b2v[n0+16];
    f16* H2 = bufB;
#pragma unroll
    for (int m=0;m<4;++m){
#pragma unroll
      for (int r=0;r<4;++r){
        int ss = m*16 + (l>>4)*4 + r;
        H2[ss*HS + n0]      = (f16)fmaxf(acc[m][0][r] + bb0, 0.f);
        H2[ss*HS + n0 + 16] = (f16)fmaxf(acc[m][1][r] + bb1, 0.f);
      }
    }
  }
  __syncthreads();

  // ---------------- Phase E: layer3 + sigmoid ----------------
  {
    f32x4 acc = {0.f,0.f,0.f,0.f};
    const f16* H2 = bufB;
#pragma unroll
    for (int kb=0; kb<4; ++kb){
      f16x8 a = *(const f16x8*)(H2 + (w*16 + tr)*HS + kb*32 + ko);
      f16x8 b = *(const f16x8*)(W3sw + (size_t)(kb*16 + tr)*32 + ko);
      acc = __builtin_amdgcn_mfma_f32_16x16x32_f16(a, b, acc, 0,0,0);
    }
    if (tr < 3){
      float bb = b3v[tr];
#pragma unroll
      for (int r=0;r<4;++r){
        int ss = w*16 + (l>>4)*4 + r;
        float c = acc[r] + bb;
        out[((size_t)blockIdx.x*64 + ss)*4 + tr] = 1.f/(1.f + __expf(-c));
      }
    }
  }
}

extern "C" void kernel_launch(void* const* d_in, const int* in_sizes, int n_in,
                              void* d_out, int out_size, void* d_ws, size_t ws_size,
                              hipStream_t stream)
{
  const float* xin     = (const float*)d_in[0];
  const float* vmc_vec = (const float*)d_in[1];
  const float* vmc_mat = (const float*)d_in[2];
  const float* vmd_vec = (const float*)d_in[3];
  const float* vmd_mat = (const float*)d_in[4];
  const float* feat_w  = (const float*)d_in[5];
  const float* w1      = (const float*)d_in[6];
  const float* b1      = (const float*)d_in[7];
  const float* w2      = (const float*)d_in[8];
  const float* b2      = (const float*)d_in[9];
  const float* w3      = (const float*)d_in[10];
  const float* b3      = (const float*)d_in[11];
  float* out = (float*)d_out;

  char* ws = (char*)d_ws;
  f16*   Weff = (f16*)(ws + WOFF_WEFF);
  f16*   W1sw = (f16*)(ws + WOFF_W1SW);
  f16*   W2sw = (f16*)(ws + WOFF_W2SW);
  f16*   W3sw = (f16*)(ws + WOFF_W3SW);
  float* vd   = (float*)(ws + WOFF_VD);
  u32*   Tm   = (u32*)(ws + WOFF_TM);

  prep_k<<<64, 256, 0, stream>>>(feat_w, vmc_vec, vmd_vec, w1, w2, w3,
                                 Weff, W1sw, W2sw, W3sw, vd);
  pack_feat_k<<<900, 256, 0, stream>>>(vmc_mat, Tm);
  pack_dens_k<<<900, 256, 0, stream>>>(vmd_mat, Tm);

  main_k<<<8192, 256, 0, stream>>>(xin, Weff, W1sw, W2sw, W3sw, vd,
                                   (const uint4*)Tm, b1, b2, b3, out);
}

// Round 4
// 183.693 us; speedup vs baseline: 8.3153x; 1.2096x over previous
//
#include <hip/hip_runtime.h>
#include <stdint.h>

typedef unsigned int u32;
typedef _Float16 f16;
typedef __attribute__((ext_vector_type(8))) _Float16 f16x8;
typedef __attribute__((ext_vector_type(4))) float f32x4;
typedef __attribute__((ext_vector_type(2))) float f32x2;

#define XMS 168   // f16 stride for X rows (336B)
#define HS  136   // f16 stride for H1 / H2 rows (272B)

// ---- workspace layout (bytes) ----
#define WOFF_WEFF 0u          // 5*32*32*2    = 10240
#define WOFF_W1SW 10240u      // 5*128*32*2   = 40960
#define WOFF_W2SW 51200u      // 4*128*32*2   = 32768
#define WOFF_W3SW 83968u      // 4*16*32*2    = 4096
#define WOFF_VD   88064u      // 48*4         = 192
#define WOFF_TM   131072u     // 3*300*300*64 = 17280000 (fp8)
#define WS_NEED   17411072u

#define TBL_SCALE 64.0f
#define TBL_INV   (1.0f/64.0f)

// ================= prep: swizzled f16 weights (1/64 folded) =================
__global__ void prep_k(const float* __restrict__ feat_w,
                       const float* __restrict__ vmc_vec,
                       const float* __restrict__ vmd_vec,
                       const float* __restrict__ w1,
                       const float* __restrict__ w2,
                       const float* __restrict__ w3,
                       f16* __restrict__ Weff, f16* __restrict__ W1sw,
                       f16* __restrict__ W2sw, f16* __restrict__ W3sw,
                       float* __restrict__ vd)
{
  const int N_WEFF = 5120, N_W1 = 20480, N_W2 = 16384, N_W3 = 2048, N_VD = 48;
  const int total = N_WEFF + N_W1 + N_W2 + N_W3 + N_VD;
  for (int t = blockIdx.x*blockDim.x + threadIdx.x; t < total; t += gridDim.x*blockDim.x){
    if (t < N_WEFF){
      int kb = t >> 10, n = (t >> 5) & 31, kk = t & 31, k = kb*32 + kk;
      float v = 0.f;
      if (n < 27 && k < 144)
        v = feat_w[n*144 + k] * 0.5f*(vmc_vec[k*300+149] + vmc_vec[k*300+150]) * TBL_INV;
      Weff[t] = (f16)v;
    } else if (t < N_WEFF + N_W1){
      int u = t - N_WEFF;
      int kb = u >> 12, n = (u >> 5) & 127, kk = u & 31, k = kb*32 + kk;
      W1sw[u] = (f16)((k < 150) ? w1[n*150 + k] : 0.f);
    } else if (t < N_WEFF + N_W1 + N_W2){
      int u = t - N_WEFF - N_W1;
      int kb = u >> 12, n = (u >> 5) & 127, kk = u & 31, k = kb*32 + kk;
      W2sw[u] = (f16)w2[n*128 + k];
    } else if (t < N_WEFF + N_W1 + N_W2 + N_W3){
      int u = t - N_WEFF - N_W1 - N_W2;
      int kb = u >> 9, n = (u >> 5) & 15, kk = u & 31, k = kb*32 + kk;
      W3sw[u] = (f16)((n < 3) ? w3[n*128 + k] : 0.f);
    } else {
      int k = t - N_WEFF - N_W1 - N_W2 - N_W3;
      vd[k] = 0.5f*(vmd_vec[k*300+149] + vmd_vec[k*300+150]) * TBL_INV;
    }
  }
}

// ---- pack feature channels: (3,48,300,300) f32 -> Tm[...][ch 0..47] fp8*64 ----
__global__ void pack_feat_k(const float* __restrict__ src, u32* __restrict__ dst)
{
  __shared__ float tile[48*304];
  int i = blockIdx.x / 300, y = blockIdx.x % 300;
  const float* sp = src + (size_t)i*48*90000 + (size_t)y*300;
  for (int t = threadIdx.x; t < 48*300; t += 256){
    int r = t / 300, x = t - r*300;
    tile[r*304 + x] = sp[(size_t)r*90000 + x] * TBL_SCALE;
  }
  __syncthreads();
  u32* dp = dst + (size_t)(i*300 + y)*300*16;
  for (int t = threadIdx.x; t < 300*12; t += 256){
    int x = t / 12, cg = t - x*12;
    int c = cg*4;
    u32 v = __builtin_amdgcn_cvt_pk_fp8_f32(tile[c*304+x],     tile[(c+1)*304+x], 0, false);
    v     = __builtin_amdgcn_cvt_pk_fp8_f32(tile[(c+2)*304+x], tile[(c+3)*304+x], v, true);
    dp[x*16 + cg] = v;
  }
}

// ---- pack density channels: (3,16,300,300) f32 -> Tm[...][ch 48..63] fp8*64 ----
__global__ void pack_dens_k(const float* __restrict__ src, u32* __restrict__ dst)
{
  __shared__ float tile[16*304];
  int i = blockIdx.x / 300, y = blockIdx.x % 300;
  const float* sp = src + (size_t)i*16*90000 + (size_t)y*300;
  for (int t = threadIdx.x; t < 16*300; t += 256){
    int r = t / 300, x = t - r*300;
    tile[r*304 + x] = sp[(size_t)r*90000 + x] * TBL_SCALE;
  }
  __syncthreads();
  u32* dp = dst + (size_t)(i*300 + y)*300*16;
  for (int t = threadIdx.x; t < 300*4; t += 256){
    int x = t / 4, cg = t - x*4;
    int c = cg*4;
    u32 v = __builtin_amdgcn_cvt_pk_fp8_f32(tile[c*304+x],     tile[(c+1)*304+x], 0, false);
    v     = __builtin_amdgcn_cvt_pk_fp8_f32(tile[(c+2)*304+x], tile[(c+3)*304+x], v, true);
    dp[x*16 + 12 + cg] = v;
  }
}

__device__ __forceinline__ void decode16(uint4 q, float* o){
  f32x2 t;
  t = __builtin_amdgcn_cvt_pk_f32_fp8(q.x, false); o[0]=t[0];  o[1]=t[1];
  t = __builtin_amdgcn_cvt_pk_f32_fp8(q.x, true ); o[2]=t[0];  o[3]=t[1];
  t = __builtin_amdgcn_cvt_pk_f32_fp8(q.y, false); o[4]=t[0];  o[5]=t[1];
  t = __builtin_amdgcn_cvt_pk_f32_fp8(q.y, true ); o[6]=t[0];  o[7]=t[1];
  t = __builtin_amdgcn_cvt_pk_f32_fp8(q.z, false); o[8]=t[0];  o[9]=t[1];
  t = __builtin_amdgcn_cvt_pk_f32_fp8(q.z, true ); o[10]=t[0]; o[11]=t[1];
  t = __builtin_amdgcn_cvt_pk_f32_fp8(q.w, false); o[12]=t[0]; o[13]=t[1];
  t = __builtin_amdgcn_cvt_pk_f32_fp8(q.w, true ); o[14]=t[0]; o[15]=t[1];
}

// ================= main fused kernel =================
__global__ __launch_bounds__(256, 4)
void main_k(const float* __restrict__ xin,
            const f16* __restrict__ WeffSw, const f16* __restrict__ W1sw,
            const f16* __restrict__ W2sw, const f16* __restrict__ W3sw,
            const float* __restrict__ vd,
            const uint4* __restrict__ Tm,
            const float* __restrict__ b1v, const float* __restrict__ b2v,
            const float* __restrict__ b3v, float* __restrict__ out)
{
  // single X buffer: Xm (fold input) -> in-place X (mlp_in) -> H2
  __shared__ __align__(16) f16 buf[64*XMS];
  __shared__ __align__(16) f16 bufH[64*HS];     // H1
  __shared__ float dLds[192];

  const int tid = threadIdx.x;
  const int l = tid & 63;
  const int w = tid >> 6;
  const size_t nidx = (size_t)blockIdx.x*64 + l;

  const float* xp = xin + nidx*6;
  float p0 = xp[0], p1 = xp[1], p2 = xp[2];

  // preload dirs for the row this (wave, lane<16) will own in Phase B
  float dd0=0.f, dd1=0.f, dd2=0.f;
  if (l < 16){
    const float* dp = xin + ((size_t)blockIdx.x*64 + w*16 + l)*6 + 3;
    dd0 = dp[0]; dd1 = dp[1]; dd2 = dp[2];
  }

  // ---------------- Phase A: sampling (waves 0..2, one plane each) ----------------
  if (w < 3){
    float cx = (w==0)? p1 : ((w==1)? p2 : p0);
    float cy = (w==0)? p2 : ((w==1)? p0 : p1);
    float fx = (cx+1.f)*0.5f*299.f, fy = (cy+1.f)*0.5f*299.f;
    float x0f = floorf(fx), y0f = floorf(fy);
    int x0 = min(max((int)x0f,0),299), y0 = min(max((int)y0f,0),299);
    int x1 = min(x0+1,299), y1 = min(y0+1,299);
    float wx = fx-x0f, wy = fy-y0f;
    float w11 = wx*wy, w10 = wy - w11, w01 = wx - w11, w00 = 1.f - wx - wy + w11;

    const uint4* Tb = Tm + (size_t)w*90000*4;
    const uint4* r00 = Tb + (size_t)(y0*300+x0)*4;
    const uint4* r01 = Tb + (size_t)(y0*300+x1)*4;
    const uint4* r10 = Tb + (size_t)(y1*300+x0)*4;
    const uint4* r11 = Tb + (size_t)(y1*300+x1)*4;
    uint4 qa[4], qb[4], qc[4], qd[4];
#pragma unroll
    for (int c4=0;c4<4;++c4){ qa[c4]=r00[c4]; qb[c4]=r01[c4]; qc[c4]=r10[c4]; qd[c4]=r11[c4]; }

    float vdw[16];
#pragma unroll
    for (int j=0;j<16;++j) vdw[j] = vd[w*16 + j];

    f16* dstrow = buf + l*XMS + w*48;
    float dacc = 0.f;
#pragma unroll
    for (int c4=0;c4<4;++c4){
      float A[16],B[16],C[16],D[16];
      decode16(qa[c4],A); decode16(qb[c4],B); decode16(qc[c4],C); decode16(qd[c4],D);
      if (c4 < 3){
        f16x8 o0, o1;
#pragma unroll
        for (int j=0;j<8;++j)
          o0[j] = (f16)(w00*A[j] + w01*B[j] + w10*C[j] + w11*D[j]);
#pragma unroll
        for (int j=0;j<8;++j)
          o1[j] = (f16)(w00*A[8+j] + w01*B[8+j] + w10*C[8+j] + w11*D[8+j]);
        *(f16x8*)(dstrow + c4*16)     = o0;
        *(f16x8*)(dstrow + c4*16 + 8) = o1;
      } else {
#pragma unroll
        for (int j=0;j<16;++j)
          dacc += (w00*A[j] + w01*B[j] + w10*C[j] + w11*D[j]) * vdw[j];
      }
    }
    dLds[w*64 + l] = dacc;
  } else {
    // wave 3: zero K-pad cols [144..160) for all rows (also X's zero cols 150..159)
    f16x8 z = 0;
    *(f16x8*)(buf + l*XMS + 144) = z;
    *(f16x8*)(buf + l*XMS + 152) = z;
  }
  __syncthreads();

  const int tr = l & 15;          // within-tile row/col
  const int ko = (l >> 4) * 8;    // k-suboffset (8 f16 per lane)

  // ---------------- Phase B: fold MFMA (in-place Xm -> X) + PE ----------------
  {
    if (w == 3){
      float ds = dLds[l] + dLds[64 + l] + dLds[128 + l];
      out[nidx*4 + 3] = fmaxf(ds, 0.f);
    }
    f32x4 fa0 = {0.f,0.f,0.f,0.f}, fa1 = {0.f,0.f,0.f,0.f};
    const f16* Arow = buf + (w*16 + tr)*XMS + ko;
#pragma unroll
    for (int kb=0; kb<5; ++kb){
      f16x8 a  = *(const f16x8*)(Arow + kb*32);
      f16x8 b0 = *(const f16x8*)(WeffSw + (size_t)(kb*32 + tr)*32 + ko);
      f16x8 b1 = *(const f16x8*)(WeffSw + (size_t)(kb*32 + 16 + tr)*32 + ko);
      fa0 = __builtin_amdgcn_mfma_f32_16x16x32_f16(a, b0, fa0, 0,0,0);
      fa1 = __builtin_amdgcn_mfma_f32_16x16x32_f16(a, b1, fa1, 0,0,0);
    }
    // pin all X writes after the fold's LDS reads (in-place safety):
    __builtin_amdgcn_sched_barrier(0);
    // false dependency so the read-independent dir writes can't be hoisted
    asm volatile("" : "+v"(dd0), "+v"(dd1), "+v"(dd2) : "v"(fa0[0]));

    const int sbase = w*16 + (l>>4)*4;
#pragma unroll
    for (int nb=0; nb<2; ++nb){
      int f = nb*16 + tr;
      if (f < 27){
#pragma unroll
        for (int r=0;r<4;++r){
          float fv = nb ? fa1[r] : fa0[r];
          f16* Xr = buf + (sbase + r)*XMS;
          Xr[f] = (f16)fv;
          float a1 = 3.14159265358979f*fv;
          float a2 = 6.28318530717959f*fv;
          Xr[30+f]  = (f16)__sinf(a1);
          Xr[57+f]  = (f16)__cosf(a1);
          Xr[84+f]  = (f16)__sinf(a2);
          Xr[111+f] = (f16)__cosf(a2);
        }
      }
    }
    if (l < 16){
      f16* Xr = buf + (w*16 + l)*XMS;
      Xr[27]=(f16)dd0; Xr[28]=(f16)dd1; Xr[29]=(f16)dd2;
      float dv[3]={dd0,dd1,dd2};
#pragma unroll
      for (int j=0;j<3;++j){
        float a1=3.14159265358979f*dv[j], a2=6.28318530717959f*dv[j];
        Xr[138+j]=(f16)__sinf(a1);
        Xr[141+j]=(f16)__cosf(a1);
        Xr[144+j]=(f16)__sinf(a2);
        Xr[147+j]=(f16)__cosf(a2);
      }
    }
  }
  __syncthreads();

  // ---------------- Phase C: layer1 (64x160 * 160x128) ----------------
  {
    f32x4 acc[4][2];
#pragma unroll
    for (int m=0;m<4;++m){ acc[m][0]=(f32x4){0.f,0.f,0.f,0.f}; acc[m][1]=(f32x4){0.f,0.f,0.f,0.f}; }
    const int n0 = w*32 + tr;
#pragma unroll
    for (int kb=0; kb<5; ++kb){
      f16x8 b0 = *(const f16x8*)(W1sw + (size_t)(kb*128 + n0)*32 + ko);
      f16x8 b1 = *(const f16x8*)(W1sw + (size_t)(kb*128 + n0 + 16)*32 + ko);
#pragma unroll
      for (int m=0;m<4;++m){
        f16x8 a = *(const f16x8*)(buf + (m*16 + tr)*XMS + kb*32 + ko);
        acc[m][0] = __builtin_amdgcn_mfma_f32_16x16x32_f16(a, b0, acc[m][0], 0,0,0);
        acc[m][1] = __builtin_amdgcn_mfma_f32_16x16x32_f16(a, b1, acc[m][1], 0,0,0);
      }
    }
    float bb0 = b1v[n0], bb1 = b1v[n0+16];
#pragma unroll
    for (int m=0;m<4;++m){
#pragma unroll
      for (int r=0;r<4;++r){
        int ss = m*16 + (l>>4)*4 + r;
        bufH[ss*HS + n0]      = (f16)fmaxf(acc[m][0][r] + bb0, 0.f);
        bufH[ss*HS + n0 + 16] = (f16)fmaxf(acc[m][1][r] + bb1, 0.f);
      }
    }
  }
  __syncthreads();

  // ---------------- Phase D: layer2 (64x128 * 128x128), H2 overlays X ----------------
  {
    f32x4 acc[4][2];
#pragma unroll
    for (int m=0;m<4;++m){ acc[m][0]=(f32x4){0.f,0.f,0.f,0.f}; acc[m][1]=(f32x4){0.f,0.f,0.f,0.f}; }
    const int n0 = w*32 + tr;
#pragma unroll
    for (int kb=0; kb<4; ++kb){
      f16x8 b0 = *(const f16x8*)(W2sw + (size_t)(kb*128 + n0)*32 + ko);
      f16x8 b1 = *(const f16x8*)(W2sw + (size_t)(kb*128 + n0 + 16)*32 + ko);
#pragma unroll
      for (int m=0;m<4;++m){
        f16x8 a = *(const f16x8*)(bufH + (m*16 + tr)*HS + kb*32 + ko);
        acc[m][0] = __builtin_amdgcn_mfma_f32_16x16x32_f16(a, b0, acc[m][0], 0,0,0);
        acc[m][1] = __builtin_amdgcn_mfma_f32_16x16x32_f16(a, b1, acc[m][1], 0,0,0);
      }
    }
    float bb0 = b2v[n0], bb1 = b2v[n0+16];
#pragma unroll
    for (int m=0;m<4;++m){
#pragma unroll
      for (int r=0;r<4;++r){
        int ss = m*16 + (l>>4)*4 + r;
        buf[ss*HS + n0]      = (f16)fmaxf(acc[m][0][r] + bb0, 0.f);
        buf[ss*HS + n0 + 16] = (f16)fmaxf(acc[m][1][r] + bb1, 0.f);
      }
    }
  }
  __syncthreads();

  // ---------------- Phase E: layer3 + sigmoid ----------------
  {
    f32x4 acc = {0.f,0.f,0.f,0.f};
#pragma unroll
    for (int kb=0; kb<4; ++kb){
      f16x8 a = *(const f16x8*)(buf + (w*16 + tr)*HS + kb*32 + ko);
      f16x8 b = *(const f16x8*)(W3sw + (size_t)(kb*16 + tr)*32 + ko);
      acc = __builtin_amdgcn_mfma_f32_16x16x32_f16(a, b, acc, 0,0,0);
    }
    if (tr < 3){
      float bb = b3v[tr];
#pragma unroll
      for (int r=0;r<4;++r){
        int ss = w*16 + (l>>4)*4 + r;
        float c = acc[r] + bb;
        out[((size_t)blockIdx.x*64 + ss)*4 + tr] = 1.f/(1.f + __expf(-c));
      }
    }
  }
}

extern "C" void kernel_launch(void* const* d_in, const int* in_sizes, int n_in,
                              void* d_out, int out_size, void* d_ws, size_t ws_size,
                              hipStream_t stream)
{
  const float* xin     = (const float*)d_in[0];
  const float* vmc_vec = (const float*)d_in[1];
  const float* vmc_mat = (const float*)d_in[2];
  const float* vmd_vec = (const float*)d_in[3];
  const float* vmd_mat = (const float*)d_in[4];
  const float* feat_w  = (const float*)d_in[5];
  const float* w1      = (const float*)d_in[6];
  const float* b1      = (const float*)d_in[7];
  const float* w2      = (const float*)d_in[8];
  const float* b2      = (const float*)d_in[9];
  const float* w3      = (const float*)d_in[10];
  const float* b3      = (const float*)d_in[11];
  float* out = (float*)d_out;

  char* ws = (char*)d_ws;
  f16*   Weff = (f16*)(ws + WOFF_WEFF);
  f16*   W1sw = (f16*)(ws + WOFF_W1SW);
  f16*   W2sw = (f16*)(ws + WOFF_W2SW);
  f16*   W3sw = (f16*)(ws + WOFF_W3SW);
  float* vd   = (float*)(ws + WOFF_VD);
  u32*   Tm   = (u32*)(ws + WOFF_TM);

  prep_k<<<64, 256, 0, stream>>>(feat_w, vmc_vec, vmd_vec, w1, w2, w3,
                                 Weff, W1sw, W2sw, W3sw, vd);
  pack_feat_k<<<900, 256, 0, stream>>>(vmc_mat, Tm);
  pack_dens_k<<<900, 256, 0, stream>>>(vmd_mat, Tm);

  main_k<<<8192, 256, 0, stream>>>(xin, Weff, W1sw, W2sw, W3sw, vd,
                                   (const uint4*)Tm, b1, b2, b3, out);
}